// Round 1
// baseline (5941.946 us; speedup 1.0000x reference)
//
#include <hip/hip_runtime.h>
#include <hip/hip_bf16.h>

#define THREADS 512

// One block per cloud. Each thread owns points {t, t+512, t+1024, ...} with
// coords and running min-distance kept in registers (statically indexed).
// Per iteration: distance to last-selected point, dist=min(dist,d), block
// argmax with first-occurrence tie-break (matches np.argmax), owner thread
// publishes the winning point's coords via LDS.
template<int NPT>
__global__ __launch_bounds__(THREADS)
void fps_kernel(const float* __restrict__ C, int n_pts, int m,
                int* __restrict__ idx_out) {
    const int b = blockIdx.x;
    const int t = threadIdx.x;
    const float* __restrict__ P = C + (size_t)b * n_pts * 3;

    float px[NPT], py[NPT], pz[NPT], dist[NPT];
#pragma unroll
    for (int j = 0; j < NPT; ++j) {
        int g = t + j * THREADS;
        if (g < n_pts) {
            px[j] = P[3 * g + 0];
            py[j] = P[3 * g + 1];
            pz[j] = P[3 * g + 2];
            dist[j] = 1e10f;
        } else {
            px[j] = 0.f; py[j] = 0.f; pz[j] = 0.f;
            dist[j] = -1.0f;   // never wins argmax (valid dists are >= 0)
        }
    }

    __shared__ float s_pv[THREADS / 64];
    __shared__ int   s_pi[THREADS / 64];
    __shared__ float s_cx, s_cy, s_cz;

    if (t == 0) {
        idx_out[(size_t)b * m] = 0;   // first index is always 0
        s_cx = px[0]; s_cy = py[0]; s_cz = pz[0];
    }
    __syncthreads();
    float lx = s_cx, ly = s_cy, lz = s_cz;

    const int wid = t >> 6;

    for (int it = 1; it < m; ++it) {
        float bv = -2.0f;
        int   bi = 0x7fffffff;
        // distance + min update + local argmax (ascending global index:
        // strictly-greater keeps the earliest occurrence)
#pragma unroll
        for (int j = 0; j < NPT; ++j) {
            float dx = __fsub_rn(px[j], lx);
            float dy = __fsub_rn(py[j], ly);
            float dz = __fsub_rn(pz[j], lz);
            float d  = __fadd_rn(__fadd_rn(__fmul_rn(dx, dx), __fmul_rn(dy, dy)),
                                 __fmul_rn(dz, dz));
            float nd = fminf(dist[j], d);
            dist[j] = nd;
            if (nd > bv) { bv = nd; bi = t + j * THREADS; }
        }
        // wave (64-lane) butterfly argmax, tie -> smaller index
#pragma unroll
        for (int off = 1; off < 64; off <<= 1) {
            float ov = __shfl_xor(bv, off);
            int   oi = __shfl_xor(bi, off);
            if (ov > bv || (ov == bv && oi < bi)) { bv = ov; bi = oi; }
        }
        if ((t & 63) == 0) { s_pv[wid] = bv; s_pi[wid] = bi; }
        __syncthreads();
        // every thread reduces the per-wave partials (uniform LDS reads)
        bv = s_pv[0]; bi = s_pi[0];
#pragma unroll
        for (int w = 1; w < THREADS / 64; ++w) {
            float v = s_pv[w]; int i2 = s_pi[w];
            if (v > bv || (v == bv && i2 < bi)) { bv = v; bi = i2; }
        }
        // owner thread publishes coords (static register select) + index
        if (t == (bi & (THREADS - 1))) {
            int slot = bi / THREADS;
            float cx = 0.f, cy = 0.f, cz = 0.f;
#pragma unroll
            for (int j = 0; j < NPT; ++j) {
                if (j == slot) { cx = px[j]; cy = py[j]; cz = pz[j]; }
            }
            s_cx = cx; s_cy = cy; s_cz = cz;
            idx_out[(size_t)b * m + it] = bi;
        }
        __syncthreads();
        lx = s_cx; ly = s_cy; lz = s_cz;
    }
}

// Gather sampled_C [batch,m,3] and sampled_F [batch,m,c] from the indices.
__global__ void gather_kernel(const float* __restrict__ C,
                              const float* __restrict__ F,
                              const int* __restrict__ idx,
                              float* __restrict__ outC,
                              float* __restrict__ outF,
                              int n_pts, int m, int c) {
    int pair = blockIdx.x;            // b*m + s
    int b = pair / m;
    int src = idx[pair];
    size_t srcbase = (size_t)b * n_pts + src;
    const float* sF = F + srcbase * (size_t)c;
    float* dF = outF + (size_t)pair * c;
    for (int i = threadIdx.x; i < c; i += blockDim.x) dF[i] = sF[i];
    if (threadIdx.x < 3)
        outC[(size_t)pair * 3 + threadIdx.x] = C[srcbase * 3 + threadIdx.x];
}

extern "C" void kernel_launch(void* const* d_in, const int* in_sizes, int n_in,
                              void* d_out, int out_size, void* d_ws, size_t ws_size,
                              hipStream_t stream) {
    const float* C = (const float*)d_in[0];
    const float* F = (const float*)d_in[1];

    int n_total = in_sizes[0] / 3;          // batch * n_pts
    int c       = in_sizes[1] / n_total;    // feature dim (128)
    int bm      = out_size / (3 + c);       // batch * m

    int batch = 8;
    if (bm % 2000 == 0) {
        int bb = bm / 2000;
        if (bb > 0 && n_total % bb == 0 && n_total / bb >= 2000) batch = bb;
    }
    int n_pts = n_total / batch;
    int m     = (n_pts < 2000) ? n_pts : 2000;

    int* idxbuf = (int*)d_ws;               // batch*m ints
    float* outC = (float*)d_out;
    float* outF = outC + (size_t)batch * m * 3;

    int npt = (n_pts + THREADS - 1) / THREADS;
#define LAUNCH_FPS(N) fps_kernel<N><<<batch, THREADS, 0, stream>>>(C, n_pts, m, idxbuf)
    if      (npt <= 8)  LAUNCH_FPS(8);
    else if (npt <= 16) LAUNCH_FPS(16);
    else if (npt <= 24) LAUNCH_FPS(24);
    else if (npt <= 32) LAUNCH_FPS(32);
    else if (npt <= 40) LAUNCH_FPS(40);
    else                LAUNCH_FPS(48);
#undef LAUNCH_FPS

    gather_kernel<<<batch * m, 128, 0, stream>>>(C, F, idxbuf, outC, outF,
                                                 n_pts, m, c);
}